// Round 7
// baseline (13.994 us; speedup 1.0000x reference)
//
#include <hip/hip_runtime.h>

// FuzzyLayer: batch=4096, in_dim=64, out_dim=64, n_rules=256, f32.
// SINGLE fused kernel. Exact sparsity: w[n,r] = min_i trapmf(x,..) > 0 with
// p ~ 1e-14 per (n,r); a w==0 rule contributes EXACTLY 0 to num and den
// (every term carries a factor of w). Sign test needs no reciprocals:
//   w>0  <=>  min_i min(x-a, d-x) > 0   (scale factors are positive)
// grid = 512 blocks x 512 thr (8 waves, 2 blocks/CU, 4 waves/SIMD).
// Block owns an 8-row slab end-to-end. Phase A: wave wv owns rules
// wv*32..wv*32+31 in 4 groups of 8 concurrent chains per lane
// (lane = sub*8 + row). Phase B: wave wv owns row wv, lane = out dim j.
// All-dead slabs (the universal case) write zeros directly (exact).

#define EPS_TRAP 1e-8f
#define EPS_F32  1.1920928955078125e-07f

constexpr int BATCH   = 4096;
constexpr int IN_DIM  = 64;
constexpr int OUT_DIM = 64;
constexpr int N_RULES = 256;
constexpr int ROWS    = 8;          // rows per block slab

__global__ __launch_bounds__(512) void fuzzy_fused_kernel(
    const float*  __restrict__ x,       // [BATCH][IN_DIM]
    const float4* __restrict__ Antes,   // [N_RULES][IN_DIM] (a,b,c,d)
    const float4* __restrict__ Cons,    // [N_RULES][OUT_DIM] (A,B,C,D)
    float* __restrict__ out)            // [BATCH][OUT_DIM]
{
    __shared__ float    xs[IN_DIM][ROWS + 1];   // [dim][row], padded
    __shared__ float    Wlds[N_RULES][ROWS];    // [rule][row]
    __shared__ unsigned fl[8];                  // 32-bit fired mask per wave

    int tid = threadIdx.x;
    int n0  = blockIdx.x * ROWS;

    // ---- stage 8x64 x-tile: threads 0..127 load one float4 each ----
    if (tid < 128) {
        int nl = tid >> 4;              // row 0..7
        int i4 = (tid & 15) * 4;        // dim group
        float4 v = *reinterpret_cast<const float4*>(x + (n0 + nl) * IN_DIM + i4);
        xs[i4 + 0][nl] = v.x;
        xs[i4 + 1][nl] = v.y;
        xs[i4 + 2][nl] = v.z;
        xs[i4 + 3][nl] = v.w;
    }
    __syncthreads();

    int lane = tid & 63;
    int wvu  = __builtin_amdgcn_readfirstlane(tid >> 6);    // wave 0..7
    int sub  = lane >> 3;               // concurrent rule slot 0..7
    int row  = lane & 7;                // row in slab
    int r0   = wvu * 32;

    // ---- phase A: per-lane chain sign test, 8 rules concurrent ----
    unsigned bits = 0;
    for (int g = 0; g < 4; ++g) {
        int r = r0 + g * 8 + sub;       // this lane's rule
        const float4* __restrict__ ap = Antes + r * IN_DIM;

        float m = 1e30f;
        for (int ib = 0; ib < IN_DIM; ib += 8) {
            #pragma unroll
            for (int io = 0; io < 8; ++io) {
                int i = ib + io;
                float4 q = ap[i];               // per-lane b128, L2-hot
                float xv = xs[i][row];          // 8-lane broadcast ds_read
                m = fminf(m, fminf(xv - q.x, q.w - xv));    // v_min3
            }
            if (!__any(m > 0.0f)) break;    // exact: min is non-increasing
        }

        unsigned long long bal = __ballot(m > 0.0f);
        if (bal) {                      // rare: exact w with true divisions
            float wm = 1e30f;
            for (int i = 0; i < IN_DIM; ++i) {
                float4 q = ap[i];
                float xv = xs[i][row];
                float rise = (xv - q.x) / (q.y - q.x + EPS_TRAP);
                float fall = (q.w - xv) / (q.w - q.z + EPS_TRAP);
                wm = fminf(wm, fminf(rise, fall));
            }
            Wlds[r][row] = fminf(fmaxf(wm, 0.0f), 1.0f);
            #pragma unroll
            for (int s = 0; s < 8; ++s)
                if ((bal >> (8 * s)) & 0xFFull) bits |= 1u << (g * 8 + s);
        }
    }
    if (lane == 0) fl[wvu] = bits;
    __syncthreads();

    // ---- phase B ----
    unsigned any = fl[0] | fl[1] | fl[2] | fl[3] |
                   fl[4] | fl[5] | fl[6] | fl[7];

    if (any == 0u) {                    // whole slab dead -> zeros (exact)
        if (tid < 128)
            reinterpret_cast<float4*>(out)[blockIdx.x * 128 + tid] =
                make_float4(0.f, 0.f, 0.f, 0.f);
        return;
    }

    // rare fired path: wave wv combines row wv over ALL fired rules
    float num = 0.0f, den = 0.0f;
    #pragma unroll
    for (int c = 0; c < 8; ++c) {
        unsigned mask = __builtin_amdgcn_readfirstlane(fl[c]);
        int rbase = c * 32;
        while (mask) {
            int lr = __ffs(mask) - 1;
            mask &= mask - 1;
            int r = rbase + lr;

            float4 cc = Cons[r * OUT_DIM + lane];   // coalesced b128
            float A = cc.x, B = cc.y, C = cc.z, D = cc.w;
            float c1 = 3.0f * (D * D - A * A);
            float c2 = 3.0f * (C * D - A * B) - c1;
            float c3 = (C - D + A - B) * (C - D - A + B);
            float d1 = 2.0f * (D - A);
            float d2 = C + A - D - B;

            float w = Wlds[r][wvu];                 // broadcast ds_read
            float tn = fmaf(fmaf(c3, w, c2), w, c1);
            num = fmaf(tn, w, num);
            den = fmaf(fmaf(d2, w, d1), w, den);
        }
    }

    float d = den + (float)N_RULES * EPS_F32;
    out[(n0 + wvu) * OUT_DIM + lane] =
        (d != 0.0f) ? (num / d) * (1.0f / 3.0f) : 0.0f;
}

extern "C" void kernel_launch(void* const* d_in, const int* in_sizes, int n_in,
                              void* d_out, int out_size, void* d_ws, size_t ws_size,
                              hipStream_t stream) {
    const float* x     = (const float*)d_in[0];
    const float* Antes = (const float*)d_in[1];
    const float* Cons  = (const float*)d_in[2];
    float* out = (float*)d_out;

    fuzzy_fused_kernel<<<BATCH / ROWS, 512, 0, stream>>>(
        x, (const float4*)Antes, (const float4*)Cons, out);
}

// Round 8
// 13.414 us; speedup vs baseline: 1.0432x; 1.0432x over previous
//
#include <hip/hip_runtime.h>

// FuzzyLayer: batch=4096, in_dim=64, out_dim=64, n_rules=256, f32.
// SINGLE fused kernel, full-chip grid (256 blocks x 1024 thr, 1 block/CU).
// Exact sparsity: w[n,r] = min_i trapmf(x,..) > 0 with p ~ 1e-14; a w==0 rule
// contributes EXACTLY 0 to num and den (every term carries a factor of w).
// Sign test needs no reciprocals: w>0 <=> min_i min(x-a, d-x) > 0.
// Block owns a 16-row slab end-to-end: per-lane chain sign test (lane =
// 4 rules x 16 rows), fired flags via ballot, rare exact-W into LDS, then
// flag-gated combine. All-dead slabs (universal case) write zeros directly.
//
// Measured ladder: 3 kernels=18.7us, 2=14.9, 1 (this config)=13.46. Kernel
// work itself is ~2.5-3us; the rest is the fixed single-dispatch replay
// floor. 512-thr/8-row variant measured 13.99 -> this 1024-thr/16-row
// config is the best-measured structure.

#define EPS_TRAP 1e-8f
#define EPS_F32  1.1920928955078125e-07f

constexpr int BATCH   = 4096;
constexpr int IN_DIM  = 64;
constexpr int OUT_DIM = 64;
constexpr int N_RULES = 256;
constexpr int ROWS    = 16;         // rows per block slab

// grid = 256 blocks x 1024 threads (16 waves, 4/SIMD, 1 block/CU).
// Phase A: wave wv owns rules wv*16..wv*16+15 in 4 groups of 4 concurrent;
//          lane = sub*16 + row (sub = lane>>4, row = lane&15).
// Phase B: wave wv owns row wv; lane = output dim j.
__global__ __launch_bounds__(1024) void fuzzy_fused_kernel(
    const float*  __restrict__ x,       // [BATCH][IN_DIM]
    const float4* __restrict__ Antes,   // [N_RULES][IN_DIM] (a,b,c,d)
    const float4* __restrict__ Cons,    // [N_RULES][OUT_DIM] (A,B,C,D)
    float* __restrict__ out)            // [BATCH][OUT_DIM]
{
    __shared__ float    xs[IN_DIM][ROWS + 1];   // [dim][row], padded
    __shared__ float    Wlds[N_RULES][ROWS];    // [rule][row]
    __shared__ unsigned fl[16];                 // 16-bit fired mask per wave

    int tid = threadIdx.x;
    int n0  = blockIdx.x * ROWS;

    // ---- stage 16x64 x-tile: threads 0..255 load one float4 each ----
    if (tid < 256) {
        int nl = tid >> 4;              // row 0..15
        int i4 = (tid & 15) * 4;        // dim group
        float4 v = *reinterpret_cast<const float4*>(x + (n0 + nl) * IN_DIM + i4);
        xs[i4 + 0][nl] = v.x;
        xs[i4 + 1][nl] = v.y;
        xs[i4 + 2][nl] = v.z;
        xs[i4 + 3][nl] = v.w;
    }
    __syncthreads();

    int lane = tid & 63;
    int wvu  = __builtin_amdgcn_readfirstlane(tid >> 6);    // wave 0..15
    int sub  = lane >> 4;               // concurrent rule slot 0..3
    int row  = lane & 15;               // row in slab
    int r0   = wvu * 16;

    // ---- phase A: per-lane chain sign test, 4 rules at a time ----
    unsigned bits = 0;
    for (int g = 0; g < 4; ++g) {
        int rb4 = r0 + g * 4;
        const float4* __restrict__ ap = Antes + (rb4 + sub) * IN_DIM;

        float m = 1e30f;
        for (int ib = 0; ib < IN_DIM; ib += 8) {
            #pragma unroll
            for (int io = 0; io < 8; ++io) {
                int i = ib + io;
                float4 q = ap[i];               // per-lane, imm-offset b128
                float xv = xs[i][row];          // 4-lane broadcast ds_read
                m = fminf(m, fminf(xv - q.x, q.w - xv));    // v_min3
            }
            if (!__any(m > 0.0f)) break;    // exact: min is non-increasing
        }

        unsigned long long bal = __ballot(m > 0.0f);
        if (bal) {                          // rare: exact w with true divisions
            const float4* __restrict__ aq = ap;
            float wm = 1e30f;
            for (int i = 0; i < IN_DIM; ++i) {
                float4 q = aq[i];
                float xv = xs[i][row];
                float rise = (xv - q.x) / (q.y - q.x + EPS_TRAP);
                float fall = (q.w - xv) / (q.w - q.z + EPS_TRAP);
                wm = fminf(wm, fminf(rise, fall));
            }
            Wlds[rb4 + sub][row] = fminf(fmaxf(wm, 0.0f), 1.0f);
            #pragma unroll
            for (int s = 0; s < 4; ++s)
                if ((bal >> (16 * s)) & 0xFFFFull) bits |= 1u << (g * 4 + s);
        }
    }
    if (lane == 0) fl[wvu] = bits;
    __syncthreads();

    // ---- phase B ----
    unsigned any = 0;
    #pragma unroll
    for (int i = 0; i < 16; ++i) any |= fl[i];

    if (any == 0u) {                    // whole slab dead -> zeros (exact)
        if (tid < 256)
            reinterpret_cast<float4*>(out)[blockIdx.x * 256 + tid] =
                make_float4(0.f, 0.f, 0.f, 0.f);
        return;
    }

    // rare fired path: wave wv combines row wv over ALL fired rules
    float num = 0.0f, den = 0.0f;
    #pragma unroll
    for (int q4 = 0; q4 < 4; ++q4) {
        unsigned long long mask =
            (unsigned long long)__builtin_amdgcn_readfirstlane(fl[q4 * 4 + 0])        |
            ((unsigned long long)__builtin_amdgcn_readfirstlane(fl[q4 * 4 + 1]) << 16) |
            ((unsigned long long)__builtin_amdgcn_readfirstlane(fl[q4 * 4 + 2]) << 32) |
            ((unsigned long long)__builtin_amdgcn_readfirstlane(fl[q4 * 4 + 3]) << 48);
        int rbase = q4 * 64;

        while (mask) {
            int lr = __ffsll(mask) - 1;
            mask &= mask - 1;
            int r = rbase + lr;

            float4 c = Cons[r * OUT_DIM + lane];    // coalesced b128
            float A = c.x, B = c.y, C = c.z, D = c.w;
            float c1 = 3.0f * (D * D - A * A);
            float c2 = 3.0f * (C * D - A * B) - c1;
            float c3 = (C - D + A - B) * (C - D - A + B);
            float d1 = 2.0f * (D - A);
            float d2 = C + A - D - B;

            float w = Wlds[r][wvu];                 // broadcast ds_read
            float tn = fmaf(fmaf(c3, w, c2), w, c1);
            num = fmaf(tn, w, num);
            den = fmaf(fmaf(d2, w, d1), w, den);
        }
    }

    float d = den + (float)N_RULES * EPS_F32;
    out[(n0 + wvu) * OUT_DIM + lane] =
        (d != 0.0f) ? (num / d) * (1.0f / 3.0f) : 0.0f;
}

extern "C" void kernel_launch(void* const* d_in, const int* in_sizes, int n_in,
                              void* d_out, int out_size, void* d_ws, size_t ws_size,
                              hipStream_t stream) {
    const float* x     = (const float*)d_in[0];
    const float* Antes = (const float*)d_in[1];
    const float* Cons  = (const float*)d_in[2];
    float* out = (float*)d_out;

    fuzzy_fused_kernel<<<BATCH / ROWS, 1024, 0, stream>>>(
        x, (const float4*)Antes, (const float4*)Cons, out);
}